// Round 1
// 1243.085 us; speedup vs baseline: 1.3356x; 1.3356x over previous
//
#include <hip/hip_runtime.h>
#include <math.h>

#define NH   16
#define NKV  4
#define HD   128
#define BSZ  4
#define TLEN 2048
#define CDIM 2048
#define MROWS (BSZ*TLEN)   // 8192

typedef short bf16x8 __attribute__((ext_vector_type(8)));
typedef float f32x4  __attribute__((ext_vector_type(4)));
typedef int   int4v  __attribute__((ext_vector_type(4)));

__device__ inline float bf2f(unsigned short h) {
  union { unsigned u; float f; } x; x.u = ((unsigned)h) << 16; return x.f;
}
__device__ inline unsigned short f2bf(float f) {
  union { float f; unsigned u; } x; x.f = f;
  unsigned u = x.u;
  return (unsigned short)((u + 0x7FFFu + ((u >> 16) & 1u)) >> 16);
}

// ---------------------------------------------------------------------------
// Dtype detector. Reads the EVEN shorts of w_proj. If the buffer holds bf16,
// every even short is a bf16 of ~N(0, 0.022) -> exponent field in ~[100,126].
// If it holds fp32, even shorts are low-mantissa garbage -> uniform exponents,
// only ~20% land in the sane window. flag=1 => bf16 storage.
// ---------------------------------------------------------------------------
__global__ void detect_kernel(const void* __restrict__ wproj, int* __restrict__ flag) {
  __shared__ int cnt;
  if (threadIdx.x == 0) cnt = 0;
  __syncthreads();
  const unsigned short* s = (const unsigned short*)wproj;
  unsigned short v = s[2 * threadIdx.x];          // 256 even shorts
  int e = (v >> 7) & 0xFF;
  if (e >= 90 && e <= 141) atomicAdd(&cnt, 1);
  __syncthreads();
  if (threadIdx.x == 0) *flag = (cnt >= 192) ? 1 : 0;
}

// Stage 8 contiguous elements (16B of bf16) into LDS; converts from fp32 if needed.
__device__ inline void stage8(short* dst, const void* src, size_t eoff, int isbf) {
  if (isbf) {
    *(int4v*)dst = *(const int4v*)((const short*)src + eoff);
  } else {
    const f32x4* f = (const f32x4*)((const float*)src + eoff);
    f32x4 a = f[0], b = f[1];
    short t[8];
    t[0] = (short)f2bf(a[0]); t[1] = (short)f2bf(a[1]);
    t[2] = (short)f2bf(a[2]); t[3] = (short)f2bf(a[3]);
    t[4] = (short)f2bf(b[0]); t[5] = (short)f2bf(b[1]);
    t[6] = (short)f2bf(b[2]); t[7] = (short)f2bf(b[3]);
    *(int4v*)dst = *(int4v*)t;
  }
}

// ---------------------------------------------------------------------------
// GEMM  C[m,n] = sum_k A[m,k] * W[n,k]   (fp32 accum, bf16 MFMA)
// 128x128 tile, BK=32, 256 threads (4 waves, each 4x4 16x16 mfma tiles).
// MODE 0: A=x, W=w_attn -> scatter q[B,16,T,128], k[B,4,T,128], vT[B,4,128,T]
// MODE 1: A=yb (always bf16), W=w_proj -> store to o0 (bf16) or o0f (fp32)
// ---------------------------------------------------------------------------
template<int MODE>
__global__ __launch_bounds__(256) void gemm_bt(
    const void* __restrict__ A, const void* __restrict__ W,
    short* __restrict__ o0, short* __restrict__ o1, short* __restrict__ o2,
    float* __restrict__ o0f, const int* __restrict__ flagp)
{
  __shared__ short As[128*32];
  __shared__ short Bs[128*32];
  const int fl  = *flagp;                 // 1 = bf16 storage
  const int aBf = (MODE == 1) ? 1 : fl;
  const int wBf = fl;
  const int tid  = threadIdx.x;
  const int wave = tid >> 6;
  const int lane = tid & 63;
  const int cl   = lane & 15;
  const int quad = lane >> 4;
  const int m0 = blockIdx.y * 128;
  const int n0 = blockIdx.x * 128;
  const int rowS = tid >> 2;            // 0..63
  const int colS = (tid & 3) << 3;      // 0,8,16,24
  const int wr = (wave >> 1) * 64;
  const int wc = (wave & 1) * 64;
  const int K = CDIM;

  f32x4 acc[4][4];
#pragma unroll
  for (int i = 0; i < 4; i++)
#pragma unroll
    for (int j = 0; j < 4; j++) acc[i][j] = (f32x4){0.f, 0.f, 0.f, 0.f};

  for (int k0 = 0; k0 < K; k0 += 32) {
    stage8(&As[rowS*32 + colS],      A, (size_t)(m0+rowS)*K    + k0 + colS, aBf);
    stage8(&As[(rowS+64)*32 + colS], A, (size_t)(m0+rowS+64)*K + k0 + colS, aBf);
    stage8(&Bs[rowS*32 + colS],      W, (size_t)(n0+rowS)*K    + k0 + colS, wBf);
    stage8(&Bs[(rowS+64)*32 + colS], W, (size_t)(n0+rowS+64)*K + k0 + colS, wBf);
    __syncthreads();
    bf16x8 af[4], bfr[4];
#pragma unroll
    for (int i = 0; i < 4; i++) af[i]  = *(const bf16x8*)(&As[(wr + i*16 + cl)*32 + quad*8]);
#pragma unroll
    for (int j = 0; j < 4; j++) bfr[j] = *(const bf16x8*)(&Bs[(wc + j*16 + cl)*32 + quad*8]);
#pragma unroll
    for (int i = 0; i < 4; i++)
#pragma unroll
      for (int j = 0; j < 4; j++)
        acc[i][j] = __builtin_amdgcn_mfma_f32_16x16x32_bf16(af[i], bfr[j], acc[i][j], 0, 0, 0);
    __syncthreads();
  }

  // C/D layout (verified m89/m91): col = lane&15, row = quad*4 + reg.
#pragma unroll
  for (int i = 0; i < 4; i++) {
#pragma unroll
    for (int j = 0; j < 4; j++) {
#pragma unroll
      for (int r = 0; r < 4; r++) {
        const int gm = m0 + wr + i*16 + quad*4 + r;
        const int gn = n0 + wc + j*16 + cl;
        const float fv = acc[i][j][r];
        if (MODE == 1) {
          if (fl) o0[(size_t)gm * CDIM + gn] = (short)f2bf(fv);
          else    o0f[(size_t)gm * CDIM + gn] = fv;
        } else {
          const int b = gm >> 11;          // /TLEN
          const int t = gm & (TLEN - 1);
          const int head = gn >> 7;        // 0..23
          const int d = gn & (HD - 1);
          const unsigned short h = f2bf(fv);
          if (head < 16) {
            o0[(((size_t)(b*NH + head) * TLEN + t) << 7) + d] = (short)h;
          } else if (head < 20) {
            o1[(((size_t)(b*NKV + (head-16)) * TLEN + t) << 7) + d] = (short)h;
          } else {
            o2[(((size_t)(b*NKV + (head-20)) * HD + d) << 11) + t] = (short)h;  // vT[b][kv][d][t]
          }
        }
      }
    }
  }
}

// ---------------------------------------------------------------------------
// RoPE in place on q [B,16,T,128] and k [B,4,T,128]; interleaved pairs.
// planes: 0..63 = q (b*16+h), 64..79 = k (b*4+kv).
// ---------------------------------------------------------------------------
__global__ __launch_bounds__(256) void rope_kernel(short* __restrict__ qb,
                                                   short* __restrict__ kb)
{
  const int idx = blockIdx.x * 256 + threadIdx.x;   // exactly 80*2048*64 threads
  const int per_plane = TLEN * 64;
  const int plane = idx / per_plane;
  const int rem = idx - plane * per_plane;
  const int t = rem >> 6;
  const int i = rem & 63;
  short* base = (plane < 64) ? (qb + (size_t)plane * (TLEN*HD))
                             : (kb + (size_t)(plane - 64) * (TLEN*HD));
  const size_t off = (size_t)t * HD + 2*i;
  const float x1 = bf2f((unsigned short)base[off]);
  const float x2 = bf2f((unsigned short)base[off+1]);
  const float inv = __expf(-0.14391156847064198f * (float)i);  // 10000^(-2i/128)
  const float ang = (float)t * inv;
  float s, c;
  sincosf(ang, &s, &c);
  base[off]   = (short)f2bf(x1*c - x2*s);
  base[off+1] = (short)f2bf(x1*s + x2*c);
}

// ---------------------------------------------------------------------------
// Flash attention (causal). Block = 4 waves; wave w owns q-rows
// [q0+16w, q0+16w+16). K-tiles of 64. QK^T / PV via mfma 16x16x32.
//
// Latency fixes vs previous version (which was latency-bound: MfmaUtil 3%,
// VALUBusy 10%, HBM 1.5%, occupancy 17%):
//  - K fragments batch-loaded into kf[4][4] (16 loads in flight, ONE wait)
//  - V fragments issued right after QK mfma, land under the softmax chain
//  - Plds is wave-private => NO __syncthreads (compiler orders via lgkmcnt)
//  - Plds XOR-swizzled ((row&7)<<3 in shorts) => kills 16-way read conflict
//  - causal balancing: block handles q-tiles qi and 31-qi => 33 tiles/block
// ---------------------------------------------------------------------------
__global__ __launch_bounds__(256) void attn_kernel(
    const short* __restrict__ qb, const short* __restrict__ kb,
    const short* __restrict__ vtb, short* __restrict__ yb)
{
  __shared__ short Plds[4][16][64];
  const int tid  = threadIdx.x;
  const int wave = tid >> 6;
  const int lane = tid & 63;
  const int cl   = lane & 15;
  const int quad = lane >> 4;
  const int bh = blockIdx.y;
  const int b = bh >> 4, h = bh & 15;
  const int kvh = h >> 2;

  const short* Qp = qb  + (size_t)(b*NH  + h)   * TLEN * HD;
  const short* Kp = kb  + (size_t)(b*NKV + kvh) * TLEN * HD;
  const short* Vp = vtb + (size_t)(b*NKV + kvh) * HD * TLEN;
  short* Pw = &Plds[wave][0][0];

  const float scale = 0.08838834764831845f;  // 1/sqrt(128)

#pragma unroll 1
  for (int pass = 0; pass < 2; ++pass) {
    const int qi = pass ? (TLEN/64 - 1 - (int)blockIdx.x) : (int)blockIdx.x;
    const int q0 = qi * 64;
    const int ntiles = qi + 1;

    bf16x8 qf[4];
    const int qrow = q0 + wave*16 + cl;
#pragma unroll
    for (int s = 0; s < 4; s++)
      qf[s] = *(const bf16x8*)(Qp + (size_t)qrow*HD + s*32 + quad*8);

    f32x4 O[8];
#pragma unroll
    for (int d = 0; d < 8; d++) O[d] = (f32x4){0.f, 0.f, 0.f, 0.f};
    float m_i[4], l_i[4];
#pragma unroll
    for (int r = 0; r < 4; r++) { m_i[r] = -1e9f; l_i[r] = 0.f; }

    for (int kt = 0; kt < ntiles; kt++) {
      const int k0 = kt * 64;

      // --- batched K fragment loads: 16 independent 16B loads in flight ---
      bf16x8 kf[4][4];
#pragma unroll
      for (int s = 0; s < 4; s++)
#pragma unroll
        for (int j = 0; j < 4; j++)
          kf[s][j] = *(const bf16x8*)(Kp + (size_t)(k0 + j*16 + cl)*HD + s*32 + quad*8);

      f32x4 S[4];
#pragma unroll
      for (int j = 0; j < 4; j++) S[j] = (f32x4){0.f, 0.f, 0.f, 0.f};
#pragma unroll
      for (int s = 0; s < 4; s++)
#pragma unroll
        for (int j = 0; j < 4; j++)
          S[j] = __builtin_amdgcn_mfma_f32_16x16x32_bf16(qf[s], kf[s][j], S[j], 0, 0, 0);

      // --- issue V loads NOW; latency hides under the softmax chain ---
      bf16x8 vf[2][8];
#pragma unroll
      for (int s2 = 0; s2 < 2; s2++)
#pragma unroll
        for (int d = 0; d < 8; d++)
          vf[s2][d] = *(const bf16x8*)(Vp + (size_t)(d*16 + cl)*TLEN + k0 + s2*32 + quad*8);

      // --- causal mask + scale ---
#pragma unroll
      for (int j = 0; j < 4; j++) {
        const int col = k0 + j*16 + cl;
#pragma unroll
        for (int r = 0; r < 4; r++) {
          const int row = q0 + wave*16 + quad*4 + r;
          const float sv = S[j][r] * scale;
          S[j][r] = (col <= row) ? sv : -1e9f;
        }
      }

      // --- online softmax (row r lives on lanes with same quad,r; 16 cols/lane-group) ---
      float alpha[4];
#pragma unroll
      for (int r = 0; r < 4; r++) {
        float mx = fmaxf(fmaxf(S[0][r], S[1][r]), fmaxf(S[2][r], S[3][r]));
#pragma unroll
        for (int off = 1; off < 16; off <<= 1) mx = fmaxf(mx, __shfl_xor(mx, off));
        const float mnew = fmaxf(m_i[r], mx);
        alpha[r] = __expf(m_i[r] - mnew);
        float rs = 0.f;
#pragma unroll
        for (int j = 0; j < 4; j++) {
          const float p = __expf(S[j][r] - mnew);
          S[j][r] = p;
          rs += p;
        }
#pragma unroll
        for (int off = 1; off < 16; off <<= 1) rs += __shfl_xor(rs, off);
        l_i[r] = l_i[r] * alpha[r] + rs;
        m_i[r] = mnew;
      }
#pragma unroll
      for (int d = 0; d < 8; d++)
#pragma unroll
        for (int r = 0; r < 4; r++) O[d][r] *= alpha[r];

      // --- P -> LDS (wave-private slice, XOR-swizzled; no barrier needed) ---
#pragma unroll
      for (int j = 0; j < 4; j++)
#pragma unroll
        for (int r = 0; r < 4; r++) {
          const int row = quad*4 + r;
          int idx = row*64 + j*16 + cl;
          idx ^= (row & 7) << 3;
          Pw[idx] = (short)f2bf(S[j][r]);
        }

      // --- PV: P (A-operand) from LDS, V from the prefetched registers ---
#pragma unroll
      for (int s2 = 0; s2 < 2; s2++) {
        int idx = cl*64 + s2*32 + quad*8;
        idx ^= (cl & 7) << 3;
        bf16x8 pf = *(const bf16x8*)(&Pw[idx]);
#pragma unroll
        for (int d = 0; d < 8; d++)
          O[d] = __builtin_amdgcn_mfma_f32_16x16x32_bf16(pf, vf[s2][d], O[d], 0, 0, 0);
      }
    }

#pragma unroll
    for (int d = 0; d < 8; d++) {
#pragma unroll
      for (int r = 0; r < 4; r++) {
        const int t = q0 + wave*16 + quad*4 + r;
        const float v = O[d][r] / l_i[r];
        yb[(size_t)(b*TLEN + t) * CDIM + h*HD + d*16 + cl] = (short)f2bf(v);
      }
    }
  }
}

// ---------------------------------------------------------------------------
extern "C" void kernel_launch(void* const* d_in, const int* in_sizes, int n_in,
                              void* d_out, int out_size, void* d_ws, size_t ws_size,
                              hipStream_t stream)
{
  const void* x      = d_in[0];   // [B,T,C]
  const void* w_attn = d_in[1];   // [3072,2048]
  const void* w_proj = d_in[2];   // [2048,2048]

  char* ws = (char*)d_ws;
  int*   flag = (int*)ws;
  short* qb  = (short*)(ws + (size_t) 1*1024*1024);   // 32 MB: q  [B,16,T,128]
  short* kb  = (short*)(ws + (size_t)33*1024*1024);   //  8 MB: k  [B,4,T,128]
  short* vtb = (short*)(ws + (size_t)41*1024*1024);   //  8 MB: vT [B,4,128,T]
  short* yb  = (short*)(ws + (size_t)49*1024*1024);   // 32 MB: y  [B,T,C]

  dim3 blk(256);
  detect_kernel<<<1, blk, 0, stream>>>(w_proj, flag);
  gemm_bt<0><<<dim3(3072/128, MROWS/128), blk, 0, stream>>>(x, w_attn, qb, kb, vtb, nullptr, flag);
  rope_kernel<<<dim3((80*TLEN*64)/256), blk, 0, stream>>>(qb, kb);
  attn_kernel<<<dim3(TLEN/128, BSZ*NH), blk, 0, stream>>>(qb, kb, vtb, yb);
  gemm_bt<1><<<dim3(CDIM/128, MROWS/128), blk, 0, stream>>>(yb, w_proj, (short*)d_out,
                                                            nullptr, nullptr, (float*)d_out, flag);
}